// Round 7
// baseline (167.705 us; speedup 1.0000x reference)
//
#include <hip/hip_runtime.h>
#include <math.h>

#define NQ    20000
#define NV    19560
#define NHEAD 4
#define DEPTHD 64

typedef __attribute__((ext_vector_type(8))) short short8;
typedef __attribute__((ext_vector_type(4))) float f32x4;

__device__ __forceinline__ ushort f2bf(float f) {
    uint32_t u = __float_as_uint(f);
    uint32_t r = (u + 0x7FFFu + ((u >> 16) & 1u)) >> 16;
    return (ushort)r;
}
__device__ __forceinline__ float bf_lo(uint32_t d) { return __uint_as_float(d << 16); }
__device__ __forceinline__ float bf_hi(uint32_t d) { return __uint_as_float(d & 0xFFFF0000u); }

// block-range constants for the fused prep kernel
#define PB_WVT0   0
#define PB_WQT0   256
#define PB_BIAS   768
#define PB_DD0    769
#define PB_DD1    (769 + 4890)          // 19560*64/256 = 4890
#define PB_QA1    (PB_DD1 + 2500)       // 20000*256/2048 = 2500
#define PB_VA1    (PB_QA1 + 2445)       // 19560*256/2048 = 2445

// ---------------------------------------------------------------------------
// Fused prep: weight transpose+cast, bias concat, ddist z-major pair table,
// and bf16 conversion of query / value activations. One launch.
// ---------------------------------------------------------------------------
__global__ __launch_bounds__(256) void prep_all(
    const float* __restrict__ Wv, const float* __restrict__ Wo,
    const float* __restrict__ Wod, const float* __restrict__ Wa,
    const float* __restrict__ bo, const float* __restrict__ bod,
    const float* __restrict__ ba, const float* __restrict__ ddist,
    const float* __restrict__ query, const float* __restrict__ value,
    ushort* __restrict__ WvT, ushort* __restrict__ WqT, float* __restrict__ bq,
    uint32_t* __restrict__ ddist2T, ushort* __restrict__ qA, ushort* __restrict__ vA)
{
    const int b = blockIdx.x;
    const int t = threadIdx.x;
    if (b < PB_WQT0) {                       // WvT[n][k] = bf16(Wv[k][n])
        WvT[b * 256 + t] = f2bf(Wv[t * 256 + b]);
    } else if (b < PB_BIAS) {                // WqT
        const int n = b - PB_WQT0;
        float w;
        if (n < 256)      w = Wo [t * 256 + n];
        else if (n < 384) w = Wod[t * 128 + (n - 256)];
        else              w = Wa [t * 128 + (n - 384)];
        WqT[n * 256 + t] = f2bf(w);
    } else if (b == PB_BIAS) {               // bias concat
        for (int i = t; i < 512; i += 256) {
            float v;
            if (i < 256)      v = bo[i];
            else if (i < 384) v = bod[i - 256];
            else              v = ba[i - 384];
            bq[i] = v;
        }
    } else if (b < PB_DD1) {                 // ddist2T[z*NV+row] = pair
        const int idx = (b - PB_DD0) * 256 + t;   // row*64+z
        const int z   = idx & 63;
        const int row = idx >> 6;
        const float lo = ddist[idx];
        const float hi = ddist[idx + ((z < 63) ? 1 : 0)];
        ddist2T[(size_t)z * NV + row] = (uint32_t)f2bf(lo) | ((uint32_t)f2bf(hi) << 16);
    } else if (b < PB_QA1) {                 // query -> bf16, 8 elems/thread
        const size_t i8 = ((size_t)(b - PB_DD1) * 256 + t) * 8;
        float4 v0 = *reinterpret_cast<const float4*>(query + i8);
        float4 v1 = *reinterpret_cast<const float4*>(query + i8 + 4);
        ushort tmp[8] = {f2bf(v0.x), f2bf(v0.y), f2bf(v0.z), f2bf(v0.w),
                         f2bf(v1.x), f2bf(v1.y), f2bf(v1.z), f2bf(v1.w)};
        *reinterpret_cast<uint4*>(qA + i8) = *reinterpret_cast<uint4*>(tmp);
    } else {                                 // value -> bf16
        const size_t i8 = ((size_t)(b - PB_QA1) * 256 + t) * 8;
        float4 v0 = *reinterpret_cast<const float4*>(value + i8);
        float4 v1 = *reinterpret_cast<const float4*>(value + i8 + 4);
        ushort tmp[8] = {f2bf(v0.x), f2bf(v0.y), f2bf(v0.z), f2bf(v0.w),
                         f2bf(v1.x), f2bf(v1.y), f2bf(v1.z), f2bf(v1.w)};
        *reinterpret_cast<uint4*>(vA + i8) = *reinterpret_cast<uint4*>(tmp);
    }
}

// ---------------------------------------------------------------------------
// Fused bf16 MFMA GEMM, both projections in ONE dispatch (overlap on GPU).
// z=0: v-proj  C(bf16)[NV,256]  = vA x WvT^T + bv     (x<2, y<153)
// z=1: q-proj  C(fp32)[NQ,512]  = qA x WqT^T + bq     (x<4, y<157)
// 128x128 tile, BK=32, 4 waves 2x2, 16x16x32 MFMA. A already bf16.
// ---------------------------------------------------------------------------
__global__ __launch_bounds__(256) void gemm_fused(
    const ushort* __restrict__ Av, const ushort* __restrict__ BTv,
    const float* __restrict__ biasv, ushort* __restrict__ Cv,
    const ushort* __restrict__ Aq, const ushort* __restrict__ BTq,
    const float* __restrict__ biasq, float* __restrict__ Cq)
{
    constexpr int K = 256, BK = 32;
    __shared__ ushort Asb[128][40];
    __shared__ ushort Bsb[128][40];

    const bool isq = (blockIdx.z == 1);
    if (!isq && (blockIdx.x >= 2 || blockIdx.y >= 153)) return;

    const ushort* A    = isq ? Aq : Av;
    const ushort* BT   = isq ? BTq : BTv;
    const float*  bias = isq ? biasq : biasv;
    const int     M    = isq ? NQ : NV;

    const int tid  = threadIdx.x;
    const int lane = tid & 63;
    const int wave = tid >> 6;
    const int wm   = wave >> 1;
    const int wn   = wave & 1;
    const int brow = blockIdx.y * 128;
    const int bcol = blockIdx.x * 128;
    const int l15  = lane & 15;
    const int kg   = lane >> 4;

    f32x4 acc[4][4] = {};

    for (int k0 = 0; k0 < K; k0 += BK) {
        #pragma unroll
        for (int i = 0; i < 2; ++i) {
            int f  = tid + i * 256;
            int r  = f >> 2;
            int c8 = (f & 3) * 8;
            uint4 av = make_uint4(0, 0, 0, 0);
            if (brow + r < M)
                av = *reinterpret_cast<const uint4*>(A + (size_t)(brow + r) * K + k0 + c8);
            *reinterpret_cast<uint4*>(&Asb[r][c8]) = av;
            uint4 bv4 = *reinterpret_cast<const uint4*>(BT + (size_t)(bcol + r) * K + k0 + c8);
            *reinterpret_cast<uint4*>(&Bsb[r][c8]) = bv4;
        }
        __syncthreads();

        short8 af[4], bfv[4];
        #pragma unroll
        for (int mf = 0; mf < 4; ++mf)
            af[mf] = *reinterpret_cast<const short8*>(&Asb[wm * 64 + mf * 16 + l15][kg * 8]);
        #pragma unroll
        for (int nf = 0; nf < 4; ++nf)
            bfv[nf] = *reinterpret_cast<const short8*>(&Bsb[wn * 64 + nf * 16 + l15][kg * 8]);
        #pragma unroll
        for (int mf = 0; mf < 4; ++mf)
            #pragma unroll
            for (int nf = 0; nf < 4; ++nf)
                acc[mf][nf] = __builtin_amdgcn_mfma_f32_16x16x32_bf16(af[mf], bfv[nf], acc[mf][nf], 0, 0, 0);
        __syncthreads();
    }

    #pragma unroll
    for (int mf = 0; mf < 4; ++mf) {
        #pragma unroll
        for (int reg = 0; reg < 4; ++reg) {
            int row = brow + wm * 64 + mf * 16 + kg * 4 + reg;
            if (row >= M) continue;
            #pragma unroll
            for (int nf = 0; nf < 4; ++nf) {
                int col = bcol + wn * 64 + nf * 16 + l15;
                float v = acc[mf][nf][reg] + bias[col];
                if (isq)
                    Cq[(size_t)row * 512 + col] = v;
                else
                    Cv[(size_t)row * 256 + col] = f2bf(v);
            }
        }
    }
}

// ---------------------------------------------------------------------------
// Sampler, 2 queries/block (lanes<32 own q0, lanes>=32 own q1 in phase A).
// ddist2T is z-plane-major: corners (x,x+1) are ADJACENT dwords -> shared
// cachelines. No __syncthreads: sm[h] is wave-private.
// ---------------------------------------------------------------------------
__global__ __launch_bounds__(256) void deform_sample(
    const float* __restrict__ qproj,     // [NQ,512]
    const ushort* __restrict__ vproj,    // [NV,256] bf16
    const uint32_t* __restrict__ ddist2T,// [64][NV] bf16-pair, z-major
    const float* __restrict__ refpts,    // [NQ,4,3]
    float* __restrict__ out)             // [NQ,256]
{
    const int b    = blockIdx.x;
    const int h    = threadIdx.x >> 6;
    const int lane = threadIdx.x & 63;
    const int j    = lane & 31;
    const int qq   = lane >> 5;
    const int q    = 2 * b + qq;

    __shared__ float2 sm[NHEAD][2][128];

    const float* qrow = qproj + (size_t)q * 512;

    // softmax over this query's 32 logits (xor<32 stays within the half)
    float logit = qrow[384 + h * 32 + j];
    float m = logit;
    #pragma unroll
    for (int o = 16; o; o >>= 1) m = fmaxf(m, __shfl_xor(m, o));
    float e = __expf(logit - m);
    float s = e;
    #pragma unroll
    for (int o = 16; o; o >>= 1) s += __shfl_xor(s, o);
    const float aw = e / s;

    const int l  = j >> 3;
    const int p  = j & 7;
    const int zi = p & 3;
    const int Wl = 160 >> l;
    const int Hl = (l == 0) ? 92 : (l == 1) ? 46 : (l == 2) ? 23 : 12;
    const int st = (l == 0) ? 0  : (l == 1) ? 14720 : (l == 2) ? 18400 : 19320;

    const int oidx = (h * 4 + l) * 8 + p;
    const float ox = qrow[oidx * 2 + 0];
    const float oy = qrow[oidx * 2 + 1];
    const float od = qrow[256 + oidx];
    const float rx = refpts[(q * 4 + zi) * 3 + 0];
    const float ry = refpts[(q * 4 + zi) * 3 + 1];
    const float rz = refpts[(q * 4 + zi) * 3 + 2];

    const float x = fmaf(rx, (float)Wl, ox - 0.5f);
    const float y = fmaf(ry, (float)Hl, oy - 0.5f);
    const float z = fmaf(rz, 64.0f,     od - 0.5f);
    const float x0f = floorf(x), y0f = floorf(y), z0f = floorf(z);
    const float fx = x - x0f, fy = y - y0f, fz = z - z0f;
    const int x0 = (int)x0f, y0 = (int)y0f, z0 = (int)z0f;

    const int z0c = min(max(z0, 0), DEPTHD - 1);
    const float wlo = (z0 >= 0 && z0 <= 63) ? (1.f - fz) : ((z0 == -1) ? fz : 0.f);
    const float whi = (z0 >= 0 && z0 <= 62) ? fz : 0.f;

    const uint32_t* dplane = ddist2T + (size_t)z0c * NV;

    #pragma unroll
    for (int c = 0; c < 4; ++c) {
        const int   cy = c >> 1, cx = c & 1;
        const int   yi = y0 + cy, xi = x0 + cx;
        const float wy = cy ? fy : (1.f - fy);
        const float wx = cx ? fx : (1.f - fx);
        const bool  valid = (xi >= 0) & (xi < Wl) & (yi >= 0) & (yi < Hl);
        const int   yc = min(max(yi, 0), Hl - 1);
        const int   xc = min(max(xi, 0), Wl - 1);
        const int   row = st + yc * Wl + xc;
        const uint32_t pd = dplane[row];           // z-major: x,x+1 share lines
        const float dscore = wlo * bf_lo(pd) + whi * bf_hi(pd);
        const float coef = valid ? (aw * wx * wy * dscore) : 0.f;
        sm[h][qq][c * 32 + j] = make_float2(coef, __int_as_float(row * 512 + h * 128));
    }
    // no barrier: wave-private LDS buffer

    // ---- phase B: both queries interleaved
    const int g   = lane >> 3;
    const int ch8 = (lane & 7) << 3;
    const uint32_t chb = (uint32_t)(ch8 << 1);
    const char* vb = (const char*)vproj;
    const float2* s0 = sm[h][0];
    const float2* s1 = sm[h][1];

    float acc0[8] = {}, acc1[8] = {};
    #pragma unroll
    for (int t = 0; t < 16; ++t) {
        const float2 w0 = s0[t * 8 + g];
        const float2 w1 = s1[t * 8 + g];
        const uint4 r0 = *reinterpret_cast<const uint4*>(vb + ((uint32_t)__float_as_int(w0.y) + chb));
        const uint4 r1 = *reinterpret_cast<const uint4*>(vb + ((uint32_t)__float_as_int(w1.y) + chb));
        acc0[0] = fmaf(w0.x, bf_lo(r0.x), acc0[0]);
        acc0[1] = fmaf(w0.x, bf_hi(r0.x), acc0[1]);
        acc0[2] = fmaf(w0.x, bf_lo(r0.y), acc0[2]);
        acc0[3] = fmaf(w0.x, bf_hi(r0.y), acc0[3]);
        acc0[4] = fmaf(w0.x, bf_lo(r0.z), acc0[4]);
        acc0[5] = fmaf(w0.x, bf_hi(r0.z), acc0[5]);
        acc0[6] = fmaf(w0.x, bf_lo(r0.w), acc0[6]);
        acc0[7] = fmaf(w0.x, bf_hi(r0.w), acc0[7]);
        acc1[0] = fmaf(w1.x, bf_lo(r1.x), acc1[0]);
        acc1[1] = fmaf(w1.x, bf_hi(r1.x), acc1[1]);
        acc1[2] = fmaf(w1.x, bf_lo(r1.y), acc1[2]);
        acc1[3] = fmaf(w1.x, bf_hi(r1.y), acc1[3]);
        acc1[4] = fmaf(w1.x, bf_lo(r1.z), acc1[4]);
        acc1[5] = fmaf(w1.x, bf_hi(r1.z), acc1[5]);
        acc1[6] = fmaf(w1.x, bf_lo(r1.w), acc1[6]);
        acc1[7] = fmaf(w1.x, bf_hi(r1.w), acc1[7]);
    }

    #pragma unroll
    for (int o = 8; o <= 32; o <<= 1) {
        #pragma unroll
        for (int k = 0; k < 8; ++k) {
            acc0[k] += __shfl_xor(acc0[k], o);
            acc1[k] += __shfl_xor(acc1[k], o);
        }
    }

    if (g == 0) {
        float* op0 = out + (size_t)(2 * b) * 256 + h * 64 + ch8;
        *reinterpret_cast<float4*>(op0)     = make_float4(acc0[0], acc0[1], acc0[2], acc0[3]);
        *reinterpret_cast<float4*>(op0 + 4) = make_float4(acc0[4], acc0[5], acc0[6], acc0[7]);
        float* op1 = op0 + 256;
        *reinterpret_cast<float4*>(op1)     = make_float4(acc1[0], acc1[1], acc1[2], acc1[3]);
        *reinterpret_cast<float4*>(op1 + 4) = make_float4(acc1[4], acc1[5], acc1[6], acc1[7]);
    }
}

// ---------------------------------------------------------------------------
extern "C" void kernel_launch(void* const* d_in, const int* in_sizes, int n_in,
                              void* d_out, int out_size, void* d_ws, size_t ws_size,
                              hipStream_t stream)
{
    const float* query  = (const float*)d_in[0];
    const float* value  = (const float*)d_in[1];
    const float* ddist  = (const float*)d_in[2];
    const float* refpts = (const float*)d_in[3];
    const float* Wv  = (const float*)d_in[6];
    const float* bv  = (const float*)d_in[7];
    const float* Wo  = (const float*)d_in[8];
    const float* bo  = (const float*)d_in[9];
    const float* Wod = (const float*)d_in[10];
    const float* bod = (const float*)d_in[11];
    const float* Wa  = (const float*)d_in[12];
    const float* ba  = (const float*)d_in[13];
    float* out = (float*)d_out;

    char* ws = (char*)d_ws;
    ushort*   vbuf    = (ushort*)ws;                               // 10,014,720 B
    float*    qbuf    = (float*)(ws + 10014720);                   // 40,960,000 B
    ushort*   WvT     = (ushort*)(ws + 10014720 + 40960000);       // 131,072 B
    ushort*   WqT     = WvT + 256 * 256;                           // 262,144 B
    float*    bq      = (float*)(WqT + 512 * 256);                 // 2,048 B
    uint32_t* ddist2T = (uint32_t*)((char*)bq + 2048);             // 5,007,360 B
    ushort*   qA      = (ushort*)((char*)ddist2T + 5007360);       // 10,240,000 B
    ushort*   vA      = qA + (size_t)NQ * 256;                     // 10,014,720 B (~76.6 MB)

    dim3 blk(256);

    prep_all<<<dim3(PB_VA1), blk, 0, stream>>>(
        Wv, Wo, Wod, Wa, bo, bod, ba, ddist, query, value,
        WvT, WqT, bq, ddist2T, qA, vA);

    gemm_fused<<<dim3(4, 157, 2), blk, 0, stream>>>(
        vA, WvT, bv, vbuf, qA, WqT, bq, qbuf);

    deform_sample<<<dim3(NQ / 2), blk, 0, stream>>>(qbuf, vbuf, ddist2T, refpts, out);
}

// Round 9
// 155.167 us; speedup vs baseline: 1.0808x; 1.0808x over previous
//
#include <hip/hip_runtime.h>
#include <math.h>

#define NQ    20000
#define NV    19560
#define NHEAD 4
#define DEPTHD 64

typedef __attribute__((ext_vector_type(8))) short short8;
typedef __attribute__((ext_vector_type(4))) float f32x4;

__device__ __forceinline__ ushort f2bf(float f) {
    uint32_t u = __float_as_uint(f);
    uint32_t r = (u + 0x7FFFu + ((u >> 16) & 1u)) >> 16;
    return (ushort)r;
}
__device__ __forceinline__ float bf_lo(uint32_t d) { return __uint_as_float(d << 16); }
__device__ __forceinline__ float bf_hi(uint32_t d) { return __uint_as_float(d & 0xFFFF0000u); }

// ---------------------------------------------------------------------------
// Weight prep (round-6 proven form)
// ---------------------------------------------------------------------------
__global__ __launch_bounds__(256) void prep_weights(
    const float* __restrict__ Wv, const float* __restrict__ Wo,
    const float* __restrict__ Wod, const float* __restrict__ Wa,
    const float* __restrict__ bo, const float* __restrict__ bod,
    const float* __restrict__ ba,
    ushort* __restrict__ WvT, ushort* __restrict__ WqT, float* __restrict__ bq)
{
    const int b = blockIdx.x;
    const int k = threadIdx.x;
    if (b < 256) {
        WvT[b * 256 + k] = f2bf(Wv[k * 256 + b]);
    } else if (b < 768) {
        const int n = b - 256;
        float w;
        if (n < 256)      w = Wo [k * 256 + n];
        else if (n < 384) w = Wod[k * 128 + (n - 256)];
        else              w = Wa [k * 128 + (n - 384)];
        WqT[n * 256 + k] = f2bf(w);
    } else {
        for (int i = k; i < 512; i += 256) {
            float v;
            if (i < 256)      v = bo[i];
            else if (i < 384) v = bod[i - 256];
            else              v = ba[i - 384];
            bq[i] = v;
        }
    }
}

// ddist pair table (row-major): ddist2[row*64+z] = (d[z],d[z+1])
__global__ __launch_bounds__(256) void prep_ddist(
    const float* __restrict__ ddist, uint32_t* __restrict__ ddist2)
{
    const int idx = blockIdx.x * 256 + threadIdx.x;
    if (idx >= NV * 64) return;
    const int z = idx & 63;
    const float lo = ddist[idx];
    const float hi = ddist[idx + ((z < 63) ? 1 : 0)];
    ddist2[idx] = (uint32_t)f2bf(lo) | ((uint32_t)f2bf(hi) << 16);
}

// ---------------------------------------------------------------------------
// bf16 MFMA GEMM (round-6 proven): C = A(fp32) x BT(bf16)^T + bias.
// ---------------------------------------------------------------------------
template<bool BF16_OUT>
__global__ __launch_bounds__(256) void gemm_mfma_bf16(
    const float* __restrict__ A, const ushort* __restrict__ BT,
    const float* __restrict__ bias, void* __restrict__ Cout,
    int M, int ldc)
{
    constexpr int K = 256, BK = 32;
    __shared__ ushort Asb[128][40];
    __shared__ ushort Bsb[128][40];

    const int tid  = threadIdx.x;
    const int lane = tid & 63;
    const int wave = tid >> 6;
    const int wm   = wave >> 1;
    const int wn   = wave & 1;
    const int brow = blockIdx.y * 128;
    const int bcol = blockIdx.x * 128;
    const int l15  = lane & 15;
    const int kg   = lane >> 4;

    f32x4 acc[4][4] = {};

    const int rA    = tid >> 1;
    const int partA = tid & 1;

    for (int k0 = 0; k0 < K; k0 += BK) {
        {
            ushort tmp[16];
            if (brow + rA < M) {
                const float* ap = A + (size_t)(brow + rA) * K + k0 + partA * 16;
                #pragma unroll
                for (int i = 0; i < 4; ++i) {
                    float4 v = *reinterpret_cast<const float4*>(ap + i * 4);
                    tmp[i * 4 + 0] = f2bf(v.x);
                    tmp[i * 4 + 1] = f2bf(v.y);
                    tmp[i * 4 + 2] = f2bf(v.z);
                    tmp[i * 4 + 3] = f2bf(v.w);
                }
            } else {
                #pragma unroll
                for (int i = 0; i < 16; ++i) tmp[i] = 0;
            }
            *reinterpret_cast<uint4*>(&Asb[rA][partA * 16 + 0]) = *reinterpret_cast<uint4*>(tmp);
            *reinterpret_cast<uint4*>(&Asb[rA][partA * 16 + 8]) = *reinterpret_cast<uint4*>(tmp + 8);
        }
        #pragma unroll
        for (int i = 0; i < 2; ++i) {
            int f  = tid + i * 256;
            int n  = f >> 2;
            int c8 = (f & 3) * 8;
            uint4 v = *reinterpret_cast<const uint4*>(BT + (size_t)(bcol + n) * K + k0 + c8);
            *reinterpret_cast<uint4*>(&Bsb[n][c8]) = v;
        }
        __syncthreads();

        short8 af[4], bfv[4];
        #pragma unroll
        for (int mf = 0; mf < 4; ++mf)
            af[mf] = *reinterpret_cast<const short8*>(&Asb[wm * 64 + mf * 16 + l15][kg * 8]);
        #pragma unroll
        for (int nf = 0; nf < 4; ++nf)
            bfv[nf] = *reinterpret_cast<const short8*>(&Bsb[wn * 64 + nf * 16 + l15][kg * 8]);
        #pragma unroll
        for (int mf = 0; mf < 4; ++mf)
            #pragma unroll
            for (int nf = 0; nf < 4; ++nf)
                acc[mf][nf] = __builtin_amdgcn_mfma_f32_16x16x32_bf16(af[mf], bfv[nf], acc[mf][nf], 0, 0, 0);
        __syncthreads();
    }

    #pragma unroll
    for (int mf = 0; mf < 4; ++mf) {
        #pragma unroll
        for (int reg = 0; reg < 4; ++reg) {
            int row = brow + wm * 64 + mf * 16 + kg * 4 + reg;
            if (row >= M) continue;
            #pragma unroll
            for (int nf = 0; nf < 4; ++nf) {
                int col = bcol + wn * 64 + nf * 16 + l15;
                float v = acc[mf][nf][reg] + bias[col];
                if (BF16_OUT)
                    ((ushort*)Cout)[(size_t)row * ldc + col] = f2bf(v);
                else
                    ((float*)Cout)[(size_t)row * ldc + col] = v;
            }
        }
    }
}

// ---------------------------------------------------------------------------
// Sampler, 2 queries/block. Phase A as round 6. Phase B: two-stage pipelined
// gathers (~16 dwordx4 outstanding per wave) to cover L2/L3 latency.
// ---------------------------------------------------------------------------
__device__ __forceinline__ void fma8(float* acc, float w, uint4 r) {
    acc[0] = fmaf(w, bf_lo(r.x), acc[0]);
    acc[1] = fmaf(w, bf_hi(r.x), acc[1]);
    acc[2] = fmaf(w, bf_lo(r.y), acc[2]);
    acc[3] = fmaf(w, bf_hi(r.y), acc[3]);
    acc[4] = fmaf(w, bf_lo(r.z), acc[4]);
    acc[5] = fmaf(w, bf_hi(r.z), acc[5]);
    acc[6] = fmaf(w, bf_lo(r.w), acc[6]);
    acc[7] = fmaf(w, bf_hi(r.w), acc[7]);
}

__global__ __launch_bounds__(256) void deform_sample(
    const float* __restrict__ qproj,    // [NQ,512]
    const ushort* __restrict__ vproj,   // [NV,256] bf16
    const uint32_t* __restrict__ ddist2,// [NV,64] bf16-pair, row-major
    const float* __restrict__ refpts,   // [NQ,4,3]
    float* __restrict__ out)            // [NQ,256]
{
    const int b    = blockIdx.x;
    const int h    = threadIdx.x >> 6;
    const int lane = threadIdx.x & 63;
    const int j    = lane & 31;
    const int qq   = lane >> 5;
    const int q    = 2 * b + qq;

    __shared__ float2 sm[NHEAD][2][128];

    const float* qrow = qproj + (size_t)q * 512;

    // softmax over this query's 32 logits (read-once -> nontemporal)
    float logit = __builtin_nontemporal_load(qrow + 384 + h * 32 + j);
    float m = logit;
    #pragma unroll
    for (int o = 16; o; o >>= 1) m = fmaxf(m, __shfl_xor(m, o));
    float e = __expf(logit - m);
    float s = e;
    #pragma unroll
    for (int o = 16; o; o >>= 1) s += __shfl_xor(s, o);
    const float aw = e / s;

    const int l  = j >> 3;
    const int p  = j & 7;
    const int zi = p & 3;
    const int Wl = 160 >> l;
    const int Hl = (l == 0) ? 92 : (l == 1) ? 46 : (l == 2) ? 23 : 12;
    const int st = (l == 0) ? 0  : (l == 1) ? 14720 : (l == 2) ? 18400 : 19320;

    const int oidx = (h * 4 + l) * 8 + p;
    const float ox = __builtin_nontemporal_load(qrow + oidx * 2 + 0);
    const float oy = __builtin_nontemporal_load(qrow + oidx * 2 + 1);
    const float od = __builtin_nontemporal_load(qrow + 256 + oidx);
    const float rx = refpts[(q * 4 + zi) * 3 + 0];
    const float ry = refpts[(q * 4 + zi) * 3 + 1];
    const float rz = refpts[(q * 4 + zi) * 3 + 2];

    const float x = fmaf(rx, (float)Wl, ox - 0.5f);
    const float y = fmaf(ry, (float)Hl, oy - 0.5f);
    const float z = fmaf(rz, 64.0f,     od - 0.5f);
    const float x0f = floorf(x), y0f = floorf(y), z0f = floorf(z);
    const float fx = x - x0f, fy = y - y0f, fz = z - z0f;
    const int x0 = (int)x0f, y0 = (int)y0f, z0 = (int)z0f;

    const int z0c = min(max(z0, 0), DEPTHD - 1);
    const float wlo = (z0 >= 0 && z0 <= 63) ? (1.f - fz) : ((z0 == -1) ? fz : 0.f);
    const float whi = (z0 >= 0 && z0 <= 62) ? fz : 0.f;

    #pragma unroll
    for (int c = 0; c < 4; ++c) {
        const int   cy = c >> 1, cx = c & 1;
        const int   yi = y0 + cy, xi = x0 + cx;
        const float wy = cy ? fy : (1.f - fy);
        const float wx = cx ? fx : (1.f - fx);
        const bool  valid = (xi >= 0) & (xi < Wl) & (yi >= 0) & (yi < Hl);
        const int   yc = min(max(yi, 0), Hl - 1);
        const int   xc = min(max(xi, 0), Wl - 1);
        const int   row = st + yc * Wl + xc;
        const uint32_t pd = ddist2[row * 64 + z0c];
        const float dscore = wlo * bf_lo(pd) + whi * bf_hi(pd);
        const float coef = valid ? (aw * wx * wy * dscore) : 0.f;
        sm[h][qq][c * 32 + j] = make_float2(coef, __int_as_float(row * 512 + h * 128));
    }
    // no barrier: wave-private LDS buffer

    // ---- phase B: two-stage pipeline, ~16 gathers outstanding
    const int g   = lane >> 3;
    const int ch8 = (lane & 7) << 3;
    const uint32_t chb = (uint32_t)(ch8 << 1);
    const char* vb = (const char*)vproj;
    const float2* s0 = sm[h][0];
    const float2* s1 = sm[h][1];

    float acc0[8] = {}, acc1[8] = {};
    uint4 rA[8], rB[8];

    // stage 1: issue 16 loads (q0[0..8), q1[0..8))
    #pragma unroll
    for (int t = 0; t < 8; ++t) {
        const float2 w = s0[t * 8 + g];
        rA[t] = *reinterpret_cast<const uint4*>(vb + ((uint32_t)__float_as_int(w.y) + chb));
    }
    #pragma unroll
    for (int t = 0; t < 8; ++t) {
        const float2 w = s1[t * 8 + g];
        rB[t] = *reinterpret_cast<const uint4*>(vb + ((uint32_t)__float_as_int(w.y) + chb));
    }
    // stage 2: drain q0 first half, reissue q0 second half
    #pragma unroll
    for (int t = 0; t < 8; ++t) {
        fma8(acc0, s0[t * 8 + g].x, rA[t]);
        const float2 w = s0[(t + 8) * 8 + g];
        rA[t] = *reinterpret_cast<const uint4*>(vb + ((uint32_t)__float_as_int(w.y) + chb));
    }
    // drain q1 first half, reissue q1 second half
    #pragma unroll
    for (int t = 0; t < 8; ++t) {
        fma8(acc1, s1[t * 8 + g].x, rB[t]);
        const float2 w = s1[(t + 8) * 8 + g];
        rB[t] = *reinterpret_cast<const uint4*>(vb + ((uint32_t)__float_as_int(w.y) + chb));
    }
    // final drains
    #pragma unroll
    for (int t = 0; t < 8; ++t) fma8(acc0, s0[(t + 8) * 8 + g].x, rA[t]);
    #pragma unroll
    for (int t = 0; t < 8; ++t) fma8(acc1, s1[(t + 8) * 8 + g].x, rB[t]);

    #pragma unroll
    for (int o = 8; o <= 32; o <<= 1) {
        #pragma unroll
        for (int k = 0; k < 8; ++k) {
            acc0[k] += __shfl_xor(acc0[k], o);
            acc1[k] += __shfl_xor(acc1[k], o);
        }
    }

    if (g == 0) {
        float* op0 = out + (size_t)(2 * b) * 256 + h * 64 + ch8;
        f32x4 o00 = {acc0[0], acc0[1], acc0[2], acc0[3]};
        f32x4 o01 = {acc0[4], acc0[5], acc0[6], acc0[7]};
        __builtin_nontemporal_store(o00, reinterpret_cast<f32x4*>(op0));
        __builtin_nontemporal_store(o01, reinterpret_cast<f32x4*>(op0 + 4));
        float* op1 = op0 + 256;
        f32x4 o10 = {acc1[0], acc1[1], acc1[2], acc1[3]};
        f32x4 o11 = {acc1[4], acc1[5], acc1[6], acc1[7]};
        __builtin_nontemporal_store(o10, reinterpret_cast<f32x4*>(op1));
        __builtin_nontemporal_store(o11, reinterpret_cast<f32x4*>(op1 + 4));
    }
}

// ---------------------------------------------------------------------------
extern "C" void kernel_launch(void* const* d_in, const int* in_sizes, int n_in,
                              void* d_out, int out_size, void* d_ws, size_t ws_size,
                              hipStream_t stream)
{
    const float* query  = (const float*)d_in[0];
    const float* value  = (const float*)d_in[1];
    const float* ddist  = (const float*)d_in[2];
    const float* refpts = (const float*)d_in[3];
    const float* Wv  = (const float*)d_in[6];
    const float* bv  = (const float*)d_in[7];
    const float* Wo  = (const float*)d_in[8];
    const float* bo  = (const float*)d_in[9];
    const float* Wod = (const float*)d_in[10];
    const float* bod = (const float*)d_in[11];
    const float* Wa  = (const float*)d_in[12];
    const float* ba  = (const float*)d_in[13];
    float* out = (float*)d_out;

    char* ws = (char*)d_ws;
    ushort*   vbuf   = (ushort*)ws;                               // 10,014,720 B
    float*    qbuf   = (float*)(ws + 10014720);                   // 40,960,000 B
    ushort*   WvT    = (ushort*)(ws + 10014720 + 40960000);       // 131,072 B
    ushort*   WqT    = WvT + 256 * 256;                           // 262,144 B
    float*    bq     = (float*)(WqT + 512 * 256);                 // 2,048 B
    uint32_t* ddist2 = (uint32_t*)((char*)bq + 2048);             // 5,007,360 B

    dim3 blk(256);

    prep_weights<<<dim3(769), blk, 0, stream>>>(Wv, Wo, Wod, Wa, bo, bod, ba, WvT, WqT, bq);
    prep_ddist<<<dim3((NV * 64 + 255) / 256), blk, 0, stream>>>(ddist, ddist2);

    gemm_mfma_bf16<true><<<dim3(2, (NV + 127) / 128), blk, 0, stream>>>(
        value, WvT, bv, vbuf, NV, 256);

    gemm_mfma_bf16<false><<<dim3(4, (NQ + 127) / 128), blk, 0, stream>>>(
        query, WqT, bq, qbuf, NQ, 512);

    deform_sample<<<dim3(NQ / 2), blk, 0, stream>>>(qbuf, vbuf, ddist2, refpts, out);
}